// Round 10
// baseline (518.391 us; speedup 1.0000x reference)
//
#include <hip/hip_runtime.h>
#include <hip/hip_bf16.h>
#include <math.h>

#define C_EMBD 1024
#define T_SEQ  2048
#define BATCH  4
#define NHEAD  16
#define DHEAD  64

typedef __attribute__((ext_vector_type(8))) short bf16x8;
typedef __attribute__((ext_vector_type(4))) float floatx4;

#if __has_builtin(__builtin_amdgcn_exp2f)
#define EXP2F __builtin_amdgcn_exp2f
#else
#define EXP2F exp2f
#endif

static __device__ __forceinline__ floatx4 mfma16(bf16x8 a, bf16x8 b, floatx4 c) {
    return __builtin_amdgcn_mfma_f32_16x16x32_bf16(a, b, c, 0, 0, 0);
}

// async global->LDS, 16B per lane; LDS dest = wave-uniform base + lane*16
static __device__ __forceinline__ void gl2lds16(const void* g, void* l) {
    __builtin_amdgcn_global_load_lds(
        (const __attribute__((address_space(1))) void*)g,
        (__attribute__((address_space(3))) void*)l, 16, 0, 0);
}

// ---------------- transpose + fp32->bf16 convert: W[K][N] -> Wt[N][K] ----------------
__global__ __launch_bounds__(256) void transpose_cvt(
        const float* __restrict__ W, __hip_bfloat16* __restrict__ Wt, int K, int N) {
    __shared__ float tile[32][33];
    const int tid = threadIdx.x;
    const int n0 = blockIdx.x * 32, k0 = blockIdx.y * 32;
    const int r = tid >> 3, c4 = (tid & 7) * 4;
    float4 v = *(const float4*)&W[(size_t)(k0 + r) * N + n0 + c4];
    tile[r][c4 + 0] = v.x; tile[r][c4 + 1] = v.y;
    tile[r][c4 + 2] = v.z; tile[r][c4 + 3] = v.w;
    __syncthreads();
    __align__(8) __hip_bfloat16 ob[4];
    ob[0] = __float2bfloat16(tile[c4 + 0][r]);
    ob[1] = __float2bfloat16(tile[c4 + 1][r]);
    ob[2] = __float2bfloat16(tile[c4 + 2][r]);
    ob[3] = __float2bfloat16(tile[c4 + 3][r]);
    *(short4*)&Wt[(size_t)(n0 + r) * K + k0 + c4] = *(short4*)ob;
}

// batched variant: four 1024x1024 transposes in one launch (z selects)
__global__ __launch_bounds__(256) void transpose_cvt4(
        const float* __restrict__ W0, const float* __restrict__ W1_,
        const float* __restrict__ W2_, const float* __restrict__ W3_,
        __hip_bfloat16* __restrict__ T0, __hip_bfloat16* __restrict__ T1,
        __hip_bfloat16* __restrict__ T2, __hip_bfloat16* __restrict__ T3) {
    __shared__ float tile[32][33];
    const float* W = (blockIdx.z == 0) ? W0 : (blockIdx.z == 1) ? W1_ :
                     (blockIdx.z == 2) ? W2_ : W3_;
    __hip_bfloat16* Wt = (blockIdx.z == 0) ? T0 : (blockIdx.z == 1) ? T1 :
                         (blockIdx.z == 2) ? T2 : T3;
    const int tid = threadIdx.x;
    const int n0 = blockIdx.x * 32, k0 = blockIdx.y * 32;
    const int r = tid >> 3, c4 = (tid & 7) * 4;
    float4 v = *(const float4*)&W[(size_t)(k0 + r) * 1024 + n0 + c4];
    tile[r][c4 + 0] = v.x; tile[r][c4 + 1] = v.y;
    tile[r][c4 + 2] = v.z; tile[r][c4 + 3] = v.w;
    __syncthreads();
    __align__(8) __hip_bfloat16 ob[4];
    ob[0] = __float2bfloat16(tile[c4 + 0][r]);
    ob[1] = __float2bfloat16(tile[c4 + 1][r]);
    ob[2] = __float2bfloat16(tile[c4 + 2][r]);
    ob[3] = __float2bfloat16(tile[c4 + 3][r]);
    *(short4*)&Wt[(size_t)(n0 + r) * 1024 + k0 + c4] = *(short4*)ob;
}

// ---------------- LayerNorm: fp32 row -> bf16 row (proven block-per-row) ----------
__global__ __launch_bounds__(256) void ln_bf16(
        const float* __restrict__ x, const float* __restrict__ g,
        const float* __restrict__ b, __hip_bfloat16* __restrict__ out) {
    const int row = blockIdx.x, tid = threadIdx.x;
    const float4 v = ((const float4*)(x + (size_t)row * C_EMBD))[tid];
    float s  = v.x + v.y + v.z + v.w;
    float sq = v.x * v.x + v.y * v.y + v.z * v.z + v.w * v.w;
    #pragma unroll
    for (int off = 1; off < 64; off <<= 1) {
        s  += __shfl_xor(s, off);
        sq += __shfl_xor(sq, off);
    }
    __shared__ float ps[4], pq[4];
    if ((tid & 63) == 0) { ps[tid >> 6] = s; pq[tid >> 6] = sq; }
    __syncthreads();
    s  = ps[0] + ps[1] + ps[2] + ps[3];
    sq = pq[0] + pq[1] + pq[2] + pq[3];
    const float mu   = s * (1.0f / C_EMBD);
    const float var  = sq * (1.0f / C_EMBD) - mu * mu;
    const float rstd = rsqrtf(var + 1e-5f);
    const float4 gv = ((const float4*)g)[tid];
    const float4 bv = ((const float4*)b)[tid];
    __align__(8) __hip_bfloat16 ob[4];
    ob[0] = __float2bfloat16((v.x - mu) * rstd * gv.x + bv.x);
    ob[1] = __float2bfloat16((v.y - mu) * rstd * gv.y + bv.y);
    ob[2] = __float2bfloat16((v.z - mu) * rstd * gv.z + bv.z);
    ob[3] = __float2bfloat16((v.w - mu) * rstd * gv.w + bv.w);
    *(short4*)&out[(size_t)row * C_EMBD + tid * 4] = *(short4*)ob;
}

// ---------------- GEMM 256x128 8-PHASE: EP1 Wo, EP3 MLP2 (N=1024 GEMMs) ----------
// Round-9 post-mortem: MLP2 on 2-phase 128^2 = 112.4us @ 611 TF (the documented
// 2-phase ceiling); 256^2-8ph can't apply at N=1024 (128 wg -> half CUs idle).
// This kernel: BM=256, BN=128, BK=64 -> grid 8x32 = 256 wg = exactly 1/CU.
// 8 waves as 4M x 2N (per-wave 64x64, acc[4][4] = 64 VGPR).  LDS 96KB
// (As 2x32KB + Bs 2x16KB) -> 1 block/CU, 2 waves/SIMD.
// Schedule (4 phases/K-tile, consumption-ordered restaging, T2+T4+T5):
//   A rows interleaved: frag mi -> row mi*64 + wr*16 + l15, so phase p=mi
//   consumes A rows [64p,64p+64); B consumed entirely in ph0.
//   Stage units (16KB = 2 gl2lds/thread): ph0 -> A(t+1)H1 [buf^1 rows 128-255],
//   ph1 -> B(t+1) [buf^1], ph2 -> A(t+2)H0 [CUR buf rows 0-127: consumed by end
//   of ph1 -> race-free].  ph3: boundary vmcnt(2) = drain t+1's 3 units (6 ops),
//   leave t+2's A-H0 (2 ops) in flight -> never 0 in-loop (T4).
//   Both-sides granule-XOR swizzle (row&7) on A and B; setprio(1) around MFMAs.
// Epilogue: scalar fp32 (16-lane 64B segments -- fine; EP0's 2B scatters were
// the round-9 problem, not fp32 rows).
template <int EP>
__global__ __launch_bounds__(512, 2) void gemm_n128_8ph(
        const __hip_bfloat16* __restrict__ A, const __hip_bfloat16* __restrict__ Bt,
        int M, int N, int K, const float* __restrict__ ba,
        float* __restrict__ of, const float* __restrict__ resid) {
    __shared__ __align__(16) __hip_bfloat16 As[2][256 * 64];  // 64 KB
    __shared__ __align__(16) __hip_bfloat16 Bs[2][128 * 64];  // 32 KB
    const int tid = threadIdx.x;

    // XCD-chunked bijective swizzle
    const int gx  = gridDim.x;
    const int nwg = gx * gridDim.y;
    const int lin = blockIdx.x + gx * blockIdx.y;
    const int cpx = nwg >> 3;
    const int wg  = (lin & 7) * cpx + (lin >> 3);
    const int by  = (wg & 7) + 8 * (wg / (gx << 3));
    const int bx  = (wg >> 3) % gx;
    const int n0  = bx * 128;
    const int m0  = by * 256;

    const int wave = tid >> 6, lane = tid & 63;
    const int l15 = lane & 15, quad = lane >> 4;
    const int wr  = wave >> 1, wc = wave & 1;     // 4M x 2N wave grid
    const int swz = l15 & 7;                      // read-side swizzle key (row&7)
    const int sr8 = tid >> 3;                     // staging sub-row 0..63
    const int sg  = (tid & 7) ^ (sr8 & 7);        // inverse-swizzled source granule

    const floatx4 z4 = {0.f, 0.f, 0.f, 0.f};
    floatx4 acc[4][4];
    #pragma unroll
    for (int i = 0; i < 4; i++)
        #pragma unroll
        for (int j = 0; j < 4; j++) acc[i][j] = z4;

    // stage one A half-tile (128 rows x 64 cols = 16KB): 2 sweeps of 64 rows
    auto stA = [&](const int buf, const int half, const int k0) {
        #pragma unroll
        for (int s = 0; s < 2; s++) {
            const int r0 = half * 128 + s * 64;
            gl2lds16(&A[(size_t)(m0 + r0 + sr8) * K + k0 + sg * 8],
                     &As[buf][r0 * 64 + wave * 512]);
        }
    };
    // stage the full B tile (128 rows = 16KB): 2 sweeps of 64 rows
    auto stB = [&](const int buf, const int k0) {
        #pragma unroll
        for (int s = 0; s < 2; s++) {
            const int r0 = s * 64;
            gl2lds16(&Bt[(size_t)(n0 + r0 + sr8) * K + k0 + sg * 8],
                     &Bs[buf][r0 * 64 + wave * 512]);
        }
    };
    auto ldA = [&](const int buf, const int mi, const int ks) -> bf16x8 {
        return *(const bf16x8*)&As[buf][(mi * 64 + wr * 16 + l15) * 64 +
                                        (((ks * 4 + quad) ^ swz) * 8)];
    };
    auto ldB = [&](const int buf, const int nj, const int ks) -> bf16x8 {
        return *(const bf16x8*)&Bs[buf][(wc * 64 + nj * 16 + l15) * 64 +
                                        (((ks * 4 + quad) ^ swz) * 8)];
    };

    const int NT = K >> 6;   // K-tiles (K%64==0, NT>=3)
    // prologue: tile0 complete (A-H0,A-H1,B = 6 ops) + tile1 A-H0 (2 ops)
    stA(0, 0, 0); stA(0, 1, 0); stB(0, 0);
    stA(1, 0, 64);
    asm volatile("s_waitcnt vmcnt(2)" ::: "memory");   // tile0 landed; t1 A-H0 in flight
    __builtin_amdgcn_s_barrier();
    asm volatile("" ::: "memory");

    for (int t = 0; t < NT; ++t) {
        const int cur = t & 1;
        const int kn1 = (t + 1) * 64, kn2 = (t + 2) * 64;
        const bool s1 = (t + 1 < NT), s2 = (t + 2 < NT);
        bf16x8 bfrag[4][2];
        #pragma unroll
        for (int p = 0; p < 4; ++p) {
            bf16x8 afr[2];
            if (p == 0) {
                #pragma unroll
                for (int nj = 0; nj < 4; nj++)
                    #pragma unroll
                    for (int ks = 0; ks < 2; ks++)
                        bfrag[nj][ks] = ldB(cur, nj, ks);
            }
            #pragma unroll
            for (int ks = 0; ks < 2; ks++)
                afr[ks] = ldA(cur, p, ks);
            // stage one 16KB unit into an already-consumed / other-buffer region
            if (p == 0)      { if (s1) stA(cur ^ 1, 1, kn1); }   // A(t+1) H1
            else if (p == 1) { if (s1) stB(cur ^ 1, kn1); }      // B(t+1)
            else if (p == 2) { if (s2) stA(cur, 0, kn2); }       // A(t+2) H0 (rows done by ph1)
            asm volatile("" ::: "memory");
            __builtin_amdgcn_s_barrier();
            asm volatile("s_waitcnt lgkmcnt(0)" ::: "memory");
            __builtin_amdgcn_s_setprio(1);
            #pragma unroll
            for (int nj = 0; nj < 4; nj++)
                #pragma unroll
                for (int ks = 0; ks < 2; ks++)
                    acc[p][nj] = mfma16(afr[ks], bfrag[nj][ks], acc[p][nj]);
            __builtin_amdgcn_s_setprio(0);
            if (p == 3) {
                if (s2) { asm volatile("s_waitcnt vmcnt(2)" ::: "memory"); }
                else    { asm volatile("s_waitcnt vmcnt(0)" ::: "memory"); }
            }
            asm volatile("" ::: "memory");
            __builtin_amdgcn_s_barrier();
            asm volatile("" ::: "memory");
        }
    }

    // epilogue: col = n0 + wc*64 + nj*16 + l15;  m = m0 + mi*64 + wr*16 + quad*4 + r
    #pragma unroll
    for (int mi = 0; mi < 4; mi++) {
        #pragma unroll
        for (int nj = 0; nj < 4; nj++) {
            const int col = n0 + wc * 64 + nj * 16 + l15;
            const float bias = ba[col];
            #pragma unroll
            for (int r = 0; r < 4; r++) {
                const int m = m0 + mi * 64 + wr * 16 + quad * 4 + r;
                const float val = acc[mi][nj][r] + bias;
                if (EP == 1) {
                    of[(size_t)m * N + col] = resid[(size_t)m * N + col] + val;
                } else {  // EP == 3
                    of[(size_t)m * N + col] += val;
                }
            }
        }
    }
}

// ---------------- GEMM 256x256 8-PHASE (T3+T4+T2+T5): EP0 QKV, EP2 MLP1 ----------
// (unchanged from round 9 — passed, LDS-slab epilogue)
template <int EP>
__global__ __launch_bounds__(512, 2) void gemm256_8ph(
        const __hip_bfloat16* __restrict__ A, const __hip_bfloat16* __restrict__ Bt,
        int M, int N, int K,
        const float* __restrict__ ba, const float* __restrict__ bb, const float* __restrict__ bc,
        __hip_bfloat16* __restrict__ o0, __hip_bfloat16* __restrict__ o1,
        __hip_bfloat16* __restrict__ o2) {
    __shared__ __align__(16) __hip_bfloat16 As[2][256 * 64];
    __shared__ __align__(16) __hip_bfloat16 Bs[2][256 * 64];
    const int tid = threadIdx.x;

    const int gx  = gridDim.x;
    const int nwg = gx * gridDim.y;
    const int lin = blockIdx.x + gx * blockIdx.y;
    const int cpx = nwg >> 3;
    const int wg  = (lin & 7) * cpx + (lin >> 3);
    const int by  = (wg & 7) + 8 * (wg / (gx << 3));
    const int bx  = (wg >> 3) % gx;
    const int n0  = bx * 256;
    const int m0  = by * 256;

    const int wave = tid >> 6, lane = tid & 63;
    const int l15 = lane & 15, quad = lane >> 4;
    const int wr  = wave >> 2, wc = wave & 3;     // 2M x 4N wave grid
    const int swz = l15 & 7;
    const int sr8 = tid >> 3;
    const int sg  = (tid & 7) ^ (sr8 & 7);

    const floatx4 z4 = {0.f, 0.f, 0.f, 0.f};
    floatx4 acc[8][4];
    #pragma unroll
    for (int i = 0; i < 8; i++)
        #pragma unroll
        for (int j = 0; j < 4; j++) acc[i][j] = z4;

    auto stA = [&](const int buf, const int half, const int k0) {
        #pragma unroll
        for (int s = 0; s < 2; s++) {
            const int r0 = half * 128 + s * 64;
            gl2lds16(&A[(size_t)(m0 + r0 + sr8) * K + k0 + sg * 8],
                     &As[buf][r0 * 64 + wave * 512]);
        }
    };
    auto stB = [&](const int buf, const int half, const int k0) {
        #pragma unroll
        for (int s = 0; s < 2; s++) {
            const int r0 = half * 128 + s * 64;
            gl2lds16(&Bt[(size_t)(n0 + r0 + sr8) * K + k0 + sg * 8],
                     &Bs[buf][r0 * 64 + wave * 512]);
        }
    };
    auto ldA = [&](const int buf, const int mi, const int ks) -> bf16x8 {
        return *(const bf16x8*)&As[buf][(mi * 32 + wr * 16 + l15) * 64 +
                                        (((ks * 4 + quad) ^ swz) * 8)];
    };
    auto ldB = [&](const int buf, const int nj, const int ks) -> bf16x8 {
        return *(const bf16x8*)&Bs[buf][(wc * 64 + nj * 16 + l15) * 64 +
                                        (((ks * 4 + quad) ^ swz) * 8)];
    };

    const int NT = K >> 6;
    stA(0, 0, 0); stB(0, 0, 0); stA(0, 1, 0); stB(0, 1, 0);
    stA(1, 0, 64); stB(1, 0, 64);
    asm volatile("s_waitcnt vmcnt(4)" ::: "memory");
    __builtin_amdgcn_s_barrier();
    asm volatile("" ::: "memory");

    for (int t = 0; t < NT; ++t) {
        const int cur = t & 1;
        const int kn1 = (t + 1) * 64, kn2 = (t + 2) * 64;
        const bool s1 = (t + 1 < NT), s2 = (t + 2 < NT);
        bf16x8 bfrag[4][2];
        #pragma unroll
        for (int p = 0; p < 4; ++p) {
            bf16x8 afr[2][2];
            if (p == 0) {
                #pragma unroll
                for (int nj = 0; nj < 4; nj++)
                    #pragma unroll
                    for (int ks = 0; ks < 2; ks++)
                        bfrag[nj][ks] = ldB(cur, nj, ks);
            }
            #pragma unroll
            for (int i = 0; i < 2; i++)
                #pragma unroll
                for (int ks = 0; ks < 2; ks++)
                    afr[i][ks] = ldA(cur, 2 * p + i, ks);
            if (p == 0)      { if (s1) stA(cur ^ 1, 1, kn1); }
            else if (p == 1) { if (s1) stB(cur ^ 1, 1, kn1); }
            else if (p == 2) { if (s2) stA(cur, 0, kn2); }
            else             { if (s2) stB(cur, 0, kn2); }
            asm volatile("" ::: "memory");
            __builtin_amdgcn_s_barrier();
            asm volatile("s_waitcnt lgkmcnt(0)" ::: "memory");
            __builtin_amdgcn_s_setprio(1);
            #pragma unroll
            for (int i = 0; i < 2; i++)
                #pragma unroll
                for (int nj = 0; nj < 4; nj++)
                    #pragma unroll
                    for (int ks = 0; ks < 2; ks++)
                        acc[2 * p + i][nj] = mfma16(afr[i][ks], bfrag[nj][ks], acc[2 * p + i][nj]);
            __builtin_amdgcn_s_setprio(0);
            if (p == 3) {
                if (s2) { asm volatile("s_waitcnt vmcnt(4)" ::: "memory"); }
                else    { asm volatile("s_waitcnt vmcnt(0)" ::: "memory"); }
            }
            asm volatile("" ::: "memory");
            __builtin_amdgcn_s_barrier();
            asm volatile("" ::: "memory");
        }
    }

    // epilogue via LDS slabs (coalesced wide stores)
    __hip_bfloat16* slab = (wc < 2) ? (&As[0][0] + wc * 16384)
                                    : (&Bs[0][0] + (wc - 2) * 16384);
    const int lid = wr * 64 + lane;

    if (EP == 0) {
        const int which = n0 >> 10;
        const int cn0   = (n0 & 1023) + wc * 64;
        const int head  = cn0 >> 6;
        const int bidx  = m0 >> 11;
        const int t0    = m0 & 2047;
        const float* bp = (which == 0) ? ba : (which == 1) ? bb : bc;
        float bias[4];
        #pragma unroll
        for (int nj = 0; nj < 4; nj++) bias[nj] = bp[cn0 + nj * 16 + l15];
        if (which < 2) {
            const float scale = (which == 0) ? 0.18033688011112042f : 1.0f;
            #pragma unroll
            for (int mi = 0; mi < 8; mi++)
                #pragma unroll
                for (int nj = 0; nj < 4; nj++)
                    #pragma unroll
                    for (int r = 0; r < 4; r++) {
                        const int row = mi * 32 + wr * 16 + quad * 4 + r;
                        slab[row * 64 + nj * 16 + l15] =
                            __float2bfloat16((acc[mi][nj][r] + bias[nj]) * scale);
                    }
            __syncthreads();
            __hip_bfloat16* dst = ((which == 0) ? o0 : o1) +
                ((size_t)(bidx * NHEAD + head) * T_SEQ + t0) * DHEAD;
            #pragma unroll
            for (int s = 0; s < 16; s++)
                *(bf16x8*)&dst[s * 1024 + lid * 8] = *(const bf16x8*)&slab[s * 1024 + lid * 8];
        } else {
            #pragma unroll
            for (int mi = 0; mi < 8; mi++)
                #pragma unroll
                for (int nj = 0; nj < 4; nj++) {
                    const int d   = nj * 16 + l15;
                    const int key = (d & 7) << 3;
                    #pragma unroll
                    for (int r = 0; r < 4; r++) {
                        const int row = mi * 32 + wr * 16 + quad * 4 + r;
                        slab[d * 256 + (row ^ key)] =
                            __float2bfloat16(acc[mi][nj][r] + bias[nj]);
                    }
                }
            __syncthreads();
            __hip_bfloat16* dst = o2 + (size_t)(bidx * NHEAD + head) * DHEAD * T_SEQ + t0;
            const int dly = lid >> 5;
            const int tly = (lid & 31) * 8;
            #pragma unroll
            for (int s = 0; s < 16; s++) {
                const int d = s * 4 + dly;
                *(bf16x8*)&dst[(size_t)d * T_SEQ + tly] =
                    *(const bf16x8*)&slab[d * 256 + (tly ^ ((d & 7) << 3))];
            }
        }
    } else {  // EP == 2: MLP1 gelu -> bf16, 128B-run stores
        float bias[4];
        #pragma unroll
        for (int nj = 0; nj < 4; nj++) bias[nj] = ba[n0 + wc * 64 + nj * 16 + l15];
        #pragma unroll
        for (int mi = 0; mi < 8; mi++)
            #pragma unroll
            for (int nj = 0; nj < 4; nj++)
                #pragma unroll
                for (int r = 0; r < 4; r++) {
                    const int row = mi * 32 + wr * 16 + quad * 4 + r;
                    const float val = acc[mi][nj][r] + bias[nj];
                    const float gl = 0.5f * val * (1.0f + erff(val * 0.70710678118654752f));
                    slab[row * 64 + nj * 16 + l15] = __float2bfloat16(gl);
                }
        __syncthreads();
        #pragma unroll
        for (int s = 0; s < 16; s++) {
            const int row = s * 16 + (lid >> 3);
            *(bf16x8*)&o0[(size_t)(m0 + row) * N + n0 + wc * 64 + (lid & 7) * 8] =
                *(const bf16x8*)&slab[row * 64 + (lid & 7) * 8];
        }
    }
}

// ---------------- Flash attention v9: LDS-staged K/V, counted-vmcnt pipeline ----------------
// (unchanged)
__global__ __launch_bounds__(256, 2) void attn_fa(
        const __hip_bfloat16* __restrict__ q, const __hip_bfloat16* __restrict__ k,
        const __hip_bfloat16* __restrict__ vt, __hip_bfloat16* __restrict__ y) {
    __shared__ __align__(16) __hip_bfloat16 Ks[2][64 * 64];
    __shared__ __align__(16) __hip_bfloat16 Vs[2][64 * 64];
    __shared__ __align__(16) __hip_bfloat16 pl[4][32 * 72];
    const int tid = threadIdx.x;
    const int wave = tid >> 6, lane = tid & 63;
    const int l15 = lane & 15, quad = lane >> 4;
    const int sw  = l15 & 7;
    const int lr  = lane >> 3;
    const int gsw = (lane & 7) ^ lr;

    const int lin  = blockIdx.x;
    const int xcd  = lin & 7;
    const int slot = lin >> 3;
    const int bh   = xcd * 8 + (slot >> 3);
    const int jA   = slot & 7;

    const __hip_bfloat16* qp = q + (size_t)bh * T_SEQ * DHEAD;
    const __hip_bfloat16* kp = k + (size_t)bh * T_SEQ * DHEAD;
    const __hip_bfloat16* vp = vt + (size_t)bh * DHEAD * T_SEQ;
    __hip_bfloat16* myp = &pl[wave][0];
    const int b = bh >> 4, head = bh & 15;
    const floatx4 z4 = {0.f, 0.f, 0.f, 0.f};

    auto stage = [&](const int buf, const int kb) {
        #pragma unroll
        for (int j = 0; j < 2; j++) {
            const int rb = wave * 16 + j * 8;
            gl2lds16(&kp[(size_t)(kb + rb + lr) * DHEAD + gsw * 8], &Ks[buf][rb * 64]);
            gl2lds16(&vp[(size_t)(rb + lr) * T_SEQ + kb + gsw * 8], &Vs[buf][rb * 64]);
        }
    };

    auto segment = [&](const int tile) {
        const int q0 = tile * 128;
        const int qw = q0 + wave * 32;
        const int cc = tile * 2 + 1;

        bf16x8 bq[2][2];
        #pragma unroll
        for (int qi = 0; qi < 2; qi++)
            #pragma unroll
            for (int h = 0; h < 2; h++)
                bq[qi][h] = *(const bf16x8*)&qp[(qw + qi * 16 + l15) * DHEAD + h * 32 + quad * 8];

        floatx4 oac[2][4];
        #pragma unroll
        for (int qi = 0; qi < 2; qi++)
            #pragma unroll
            for (int nd = 0; nd < 4; nd++) oac[qi][nd] = z4;
        float li[2] = {0.f, 0.f};

        stage(0, 0);

        for (int t = 0; t <= cc; t++) {
            const int cur = t & 1;
            if (t < cc) {
                stage(cur ^ 1, (t + 1) * 64);
                asm volatile("s_waitcnt vmcnt(4)" ::: "memory");
            } else {
                asm volatile("s_waitcnt vmcnt(0)" ::: "memory");
            }
            __builtin_amdgcn_s_barrier();
            asm volatile("" ::: "memory");

            const int kb = t * 64;
            const bool act = (kb <= qw + 31);
            if (act) {
                const bool dg = (kb + 63 > qw);
                bf16x8 kf[4][2];
                #pragma unroll
                for (int nt = 0; nt < 4; nt++)
                    #pragma unroll
                    for (int h = 0; h < 2; h++)
                        kf[nt][h] = *(const bf16x8*)&Ks[cur][(nt * 16 + l15) * 64 + (((h * 4 + quad) ^ sw) * 8)];
                floatx4 sa[2][4];
                #pragma unroll
                for (int qi = 0; qi < 2; qi++)
                    #pragma unroll
                    for (int nt = 0; nt < 4; nt++) sa[qi][nt] = z4;
                #pragma unroll
                for (int nt = 0; nt < 4; nt++)
                    #pragma unroll
                    for (int h = 0; h < 2; h++) {
                        sa[0][nt] = mfma16(kf[nt][h], bq[0][h], sa[0][nt]);
                        sa[1][nt] = mfma16(kf[nt][h], bq[1][h], sa[1][nt]);
                    }
                if (dg) {
                    #pragma unroll
                    for (int qi = 0; qi < 2; qi++)
                        #pragma unroll
                        for (int nt = 0; nt < 4; nt++)
                            #pragma unroll
                            for (int r = 0; r < 4; r++)
                                if (kb + nt * 16 + quad * 4 + r > qw + qi * 16 + l15)
                                    sa[qi][nt][r] = -INFINITY;
                }
                #pragma unroll
                for (int qi = 0; qi < 2; qi++) {
                    float sm = 0.f;
                    #pragma unroll
                    for (int nt = 0; nt < 4; nt++) {
                        __align__(8) __hip_bfloat16 pk[4];
                        #pragma unroll
                        for (int r = 0; r < 4; r++) {
                            const float p = EXP2F(sa[qi][nt][r]);
                            sm += p;
                            pk[r] = __float2bfloat16(p);
                        }
                        *(short4*)&myp[(qi * 16 + l15) * 72 + nt * 16 + quad * 4] = *(short4*)pk;
                    }
                    li[qi] += sm;
                }
                bf16x8 vf[4][2];
                #pragma unroll
                for (int nd = 0; nd < 4; nd++)
                    #pragma unroll
                    for (int kh = 0; kh < 2; kh++)
                        vf[nd][kh] = *(const bf16x8*)&Vs[cur][(nd * 16 + l15) * 64 + (((kh * 4 + quad) ^ sw) * 8)];
                asm volatile("s_waitcnt lgkmcnt(0)" ::: "memory");
                bf16x8 pf[2][2];
                #pragma unroll
                for (int qi = 0; qi < 2; qi++)
                    #pragma unroll
                    for (int kh = 0; kh < 2; kh++)
                        pf[qi][kh] = *(const bf16x8*)&myp[(qi * 16 + l15) * 72 + kh * 32 + quad * 8];
                #pragma unroll
                for (int nd = 0; nd < 4; nd++)
                    #pragma unroll
                    for (int kh = 0; kh < 2; kh++) {
                        oac[0][nd] = mfma16(vf[nd][kh], pf[0][kh], oac[0][nd]);
                        oac[1][nd] = mfma16(vf[nd][kh], pf[1][kh], oac[1][nd]);
                    }
            }
            asm volatile("" ::: "memory");
            __builtin_amdgcn_s_barrier();
        }

        float inv[2];
        #pragma unroll
        for (int qi = 0; qi < 2; qi++) {
            float l = li[qi];
            l += __shfl_xor(l, 16);
            l += __shfl_xor(l, 32);
            inv[qi] = 1.0f / l;
        }
        #pragma unroll
        for (int qi = 0; qi < 2; qi++)
            #pragma unroll
            for (int nd = 0; nd < 4; nd++) {
                __align__(8) __hip_bfloat16 ok[4];
                #pragma unroll
                for (int r = 0; r < 4; r++) ok[r] = __float2bfloat16(oac[qi][nd][r] * inv[qi]);
                *(short4*)&myp[(qi * 16 + l15) * 72 + nd * 16 + quad * 4] = *(short4*)ok;
            }
        asm volatile("s_waitcnt lgkmcnt(0)" ::: "memory");
        #pragma unroll
        for (int half = 0; half < 2; half++) {
            const int row = half * 16 + (lane >> 2);
            const int cb  = (lane & 3) * 16;
            const bf16x8 v0 = *(const bf16x8*)&myp[row * 72 + cb];
            const bf16x8 v1 = *(const bf16x8*)&myp[row * 72 + cb + 8];
            __hip_bfloat16* yr = &y[(size_t)(b * T_SEQ + qw + row) * C_EMBD + head * DHEAD + cb];
            *(bf16x8*)yr       = v0;
            *(bf16x8*)(yr + 8) = v1;
        }
        asm volatile("s_waitcnt vmcnt(0)" ::: "memory");
    };

    segment(jA);
    segment(15 - jA);
}

extern "C" void kernel_launch(void* const* d_in, const int* in_sizes, int n_in,
                              void* d_out, int out_size, void* d_ws, size_t ws_size,
                              hipStream_t stream) {
    const float* x     = (const float*)d_in[0];
    const float* ln1_g = (const float*)d_in[1];
    const float* ln1_b = (const float*)d_in[2];
    const float* Wq    = (const float*)d_in[3];
    const float* bq    = (const float*)d_in[4];
    const float* Wk    = (const float*)d_in[5];
    const float* bk    = (const float*)d_in[6];
    const float* Wv    = (const float*)d_in[7];
    const float* bv    = (const float*)d_in[8];
    const float* Wo    = (const float*)d_in[9];
    const float* bo    = (const float*)d_in[10];
    const float* ln2_g = (const float*)d_in[11];
    const float* ln2_b = (const float*)d_in[12];
    const float* W1    = (const float*)d_in[13];
    const float* b1    = (const float*)d_in[14];
    const float* W2    = (const float*)d_in[15];
    const float* b2    = (const float*)d_in[16];
    float* out = (float*)d_out;

    char* ws = (char*)d_ws;
    __hip_bfloat16* wqkvt = (__hip_bfloat16*)(ws);              // [3072][1024]
    __hip_bfloat16* wot   = (__hip_bfloat16*)(ws + 6291456);    // [1024][1024]
    __hip_bfloat16* w1t   = (__hip_bfloat16*)(ws + 8388608);    // [4096][1024]
    __hip_bfloat16* w2t   = (__hip_bfloat16*)(ws + 16777216);   // [1024][4096]
    __hip_bfloat16* hbuf  = (__hip_bfloat16*)(ws + 25165824);   // [8192][1024]
    __hip_bfloat16* qbuf  = (__hip_bfloat16*)(ws + 41943040);   // [64][2048][64]
    __hip_bfloat16* kbuf  = (__hip_bfloat16*)(ws + 58720256);   // [64][2048][64]
    __hip_bfloat16* vbuf  = (__hip_bfloat16*)(ws + 75497472);   // [64][64][2048]
    __hip_bfloat16* ybuf  = (__hip_bfloat16*)(ws + 92274688);   // [8192][1024]
    __hip_bfloat16* mbuf  = (__hip_bfloat16*)(ws + 41943040);   // [8192][4096], overlays q/k/v/y

    transpose_cvt4<<<dim3(32, 32, 4), 256, 0, stream>>>(
        Wq, Wk, Wv, Wo, wqkvt, wqkvt + 1024 * 1024, wqkvt + 2048 * 1024, wot);
    transpose_cvt<<<dim3(128, 32), 256, 0, stream>>>(W1, w1t, 1024, 4096);
    transpose_cvt<<<dim3(32, 128), 256, 0, stream>>>(W2, w2t, 4096, 1024);

    ln_bf16<<<8192, 256, 0, stream>>>(x, ln1_g, ln1_b, hbuf);

    gemm256_8ph<0><<<dim3(12, 32), 512, 0, stream>>>(hbuf, wqkvt, 8192, 3072, 1024,
        bq, bk, bv, qbuf, kbuf, vbuf);

    attn_fa<<<dim3(512), 256, 0, stream>>>(qbuf, kbuf, vbuf, ybuf);

    gemm_n128_8ph<1><<<dim3(8, 32), 512, 0, stream>>>(ybuf, wot, 8192, 1024, 1024,
        bo, out, x);

    ln_bf16<<<8192, 256, 0, stream>>>(out, ln2_g, ln2_b, hbuf);

    gemm256_8ph<2><<<dim3(16, 32), 512, 0, stream>>>(hbuf, w1t, 8192, 4096, 1024,
        b1, nullptr, nullptr, mbuf, nullptr, nullptr);

    gemm_n128_8ph<3><<<dim3(8, 32), 512, 0, stream>>>(mbuf, w2t, 8192, 1024, 4096,
        b2, out, nullptr);
}